// Round 9
// baseline (997.375 us; speedup 1.0000x reference)
//
#include <hip/hip_runtime.h>
#include <hip/hip_fp16.h>
#include <cstddef>

// ---------------------------------------------------------------------------
// SpatialAudioRenderer on MI355X — v9: analytic BN1 stats + prefetched final.
//
// R8: 972us. conv1_stats (~110us) replaced by input autocorrelation (conv1 is
// linear: mean/var of conv1 output = quadratic form in Rx[i,i',delta<=6], 30
// scalars, memory-bound ~4us). conv2_final adopts stats kernel's conv2
// mapping (2M x 8N per wave, register-prefetched A: 2 loads/chunk vs 8
// unprefetched -> removes the per-chunk VMEM latency stall).
// ---------------------------------------------------------------------------

#define TLEN 131072
#define NB 8
#define NICH 2
#define NHID 64
#define NH2 128
#define EPSV 1e-5f
#define CNTF 1048576.0f  // NB * TLEN
#define FT 120           // final-kernel output tile
#define FGRID 1093       // ceil(TLEN / FT)
#define XCH 2048         // xcorr t-chunk

typedef _Float16 f16x8 __attribute__((ext_vector_type(8)));
typedef float f32x4 __attribute__((ext_vector_type(4)));

__device__ __forceinline__ float lrelu(float v) { return v >= 0.f ? v : 0.2f * v; }
__device__ __forceinline__ unsigned short h16(float v) {
  return __half_as_ushort(__float2half(v));
}
__device__ __forceinline__ float fh16(unsigned short u) {
  return __half2float(__ushort_as_half(u));
}

// ---------------------------------------------------------------------------
// Kernel 0: weight prep, fragment-contiguous layouts (see v8).
// ---------------------------------------------------------------------------
__global__ __launch_bounds__(256) void prep_weights(
    const float* __restrict__ W2c, const float* __restrict__ RW2c,
    const float* __restrict__ RW3c,
    unsigned short* __restrict__ w2sp, unsigned short* __restrict__ w2re,
    unsigned short* __restrict__ w3g)
{
  int e = blockIdx.x * 256 + threadIdx.x;
  if (e < 114688) {
    int e2 = (e >= 57344) ? e - 57344 : e;
    int frag = e2 >> 9, within = e2 & 511;
    int c = frag >> 3, mt = frag & 7;
    int mn = within >> 5, kk = within & 31;
    int o = mt * 16 + mn;
    int tap = c >> 1, ch = (c & 1) * 32 + kk;
    const float* src = (e >= 57344) ? RW2c : W2c;
    unsigned short* dst = (e >= 57344) ? w2re : w2sp;
    dst[e2] = h16(src[(o * 64 + ch) * 7 + tap]);
  } else if (e < 116736) {
    int e2 = e - 114688;
    int c = e2 >> 9, within = e2 & 511;
    int m = within >> 5, kk = within & 31;
    int ch = c * 32 + kk;
    w3g[e2] = (m < 14) ? h16(RW3c[((m / 7) * 128 + ch) * 7 + (m % 7)])
                       : (unsigned short)0;
  }
}

// ---------------------------------------------------------------------------
// Kernel A: input autocorrelation partials for analytic conv1 BN stats.
// Output per block: 30 floats = Rx[i][i'][d] (i*14+i2*7+d, d=0..6) + A1[2].
// Products assigned to base index t (zero-extension handled by zs zeroing).
// ---------------------------------------------------------------------------
__global__ __launch_bounds__(256) void xcorr_stats(
    const float* __restrict__ z, float* __restrict__ partials)
{
  const int b = blockIdx.x >> 6;             // 64 chunks of XCH per batch
  const int t0 = (blockIdx.x & 63) * XCH;
  __shared__ float zs[2][XCH + 8];
  __shared__ float redx[4][30];
  for (int i = 0; i < 2; ++i)
    for (int j = threadIdx.x; j < XCH + 7; j += 256) {
      int tg = t0 + j;
      zs[i][j] = (tg < TLEN) ? z[(b * 2 + i) * TLEN + tg] : 0.f;
    }
  __syncthreads();

  float acc[30];
  #pragma unroll
  for (int q = 0; q < 30; ++q) acc[q] = 0.f;
  const int tb = threadIdx.x * 8;
  #pragma unroll
  for (int tt = 0; tt < 8; ++tt) {
    int j = tb + tt;
    float z0 = zs[0][j], z1 = zs[1][j];
    acc[28] += z0; acc[29] += z1;
    #pragma unroll
    for (int d = 0; d < 7; ++d) {
      float a0 = zs[0][j + d], a1 = zs[1][j + d];
      acc[d]      += z0 * a0;
      acc[7 + d]  += z0 * a1;
      acc[14 + d] += z1 * a0;
      acc[21 + d] += z1 * a1;
    }
  }
  #pragma unroll
  for (int q = 0; q < 30; ++q)
    #pragma unroll
    for (int m = 1; m <= 32; m <<= 1)
      acc[q] += __shfl_xor(acc[q], m, 64);
  const int lane = threadIdx.x & 63, wv = threadIdx.x >> 6;
  if (lane == 0)
    #pragma unroll
    for (int q = 0; q < 30; ++q) redx[wv][q] = acc[q];
  __syncthreads();
  if (threadIdx.x < 30)
    partials[blockIdx.x * 30 + threadIdx.x] =
        redx[0][threadIdx.x] + redx[1][threadIdx.x] +
        redx[2][threadIdx.x] + redx[3][threadIdx.x];
}

// ---------------------------------------------------------------------------
// Kernel B: assemble coef1 from Rx/A1.  S1 = N*b1 + sum W*A1;
// sum(y^2) = sum_{ik,i'k'} W W Rx[i,i',k'-k];  S2 = 2 b1 S1 - N b1^2 + syy.
// (Edge terms ~6/1e6 rel omitted — invisible at bf16-output ulp.)
// ---------------------------------------------------------------------------
__global__ __launch_bounds__(256) void assemble_coef1(
    const float* __restrict__ partials, int nblocks,
    const float* __restrict__ W1c, const float* __restrict__ b1c,
    const float* __restrict__ g, const float* __restrict__ be,
    float* __restrict__ coef)
{
  __shared__ float R[30];
  __shared__ float w1s[64 * 14];
  for (int e = threadIdx.x; e < 64 * 14; e += 256) w1s[e] = W1c[e];
  if (threadIdx.x < 30) {
    float s = 0.f;
    for (int j = 0; j < nblocks; ++j) s += partials[j * 30 + threadIdx.x];
    R[threadIdx.x] = s;
  }
  __syncthreads();
  if (threadIdx.x < 64) {
    int o = threadIdx.x;
    const float* w = &w1s[o * 14];
    float b1v = b1c[o];
    float sy = 0.f;
    #pragma unroll
    for (int i = 0; i < 2; ++i)
      #pragma unroll
      for (int k = 0; k < 7; ++k) sy += w[i * 7 + k] * R[28 + i];
    float syy = 0.f;
    #pragma unroll
    for (int i = 0; i < 2; ++i)
      #pragma unroll
      for (int k = 0; k < 7; ++k) {
        float wv = w[i * 7 + k];
        #pragma unroll
        for (int i2 = 0; i2 < 2; ++i2)
          #pragma unroll
          for (int k2 = 0; k2 < 7; ++k2) {
            int d = k2 - k;
            float r = (d >= 0) ? R[i * 14 + i2 * 7 + d]
                               : R[i2 * 14 + i * 7 - d];
            syy += wv * w[i2 * 7 + k2] * r;
          }
      }
    float S1 = CNTF * b1v + sy;
    float S2 = 2.f * b1v * S1 - CNTF * b1v * b1v + syy;
    float mean = S1 / CNTF;
    float var = S2 / CNTF - mean * mean;
    float a = g[o] * rsqrtf(var + EPSV);
    coef[o] = a;
    coef[64 + o] = be[o] - mean * a;
  }
}

// ---------------------------------------------------------------------------
// Kernel 2: reduce conv2-stats partials -> bn affine coefs.
// ---------------------------------------------------------------------------
__global__ __launch_bounds__(256) void reduce_coef(
    const float* __restrict__ partials, int nblocks, int C,
    const float* __restrict__ g, const float* __restrict__ be,
    float* __restrict__ coef)
{
  const int c = blockIdx.x;
  float s = 0.f, ss = 0.f;
  for (int j = threadIdx.x; j < nblocks; j += 256) {
    s  += partials[j * 2 * C + c];
    ss += partials[j * 2 * C + C + c];
  }
  #pragma unroll
  for (int off = 32; off >= 1; off >>= 1) {
    s  += __shfl_down(s, off, 64);
    ss += __shfl_down(ss, off, 64);
  }
  __shared__ float rs[4], rss[4];
  const int lane = threadIdx.x & 63, wv = threadIdx.x >> 6;
  if (lane == 0) { rs[wv] = s; rss[wv] = ss; }
  __syncthreads();
  if (threadIdx.x == 0) {
    float st  = rs[0] + rs[1] + rs[2] + rs[3];
    float sst = rss[0] + rss[1] + rss[2] + rss[3];
    float mean = st / CNTF;
    float var  = sst / CNTF - mean * mean;
    float a = g[c] * rsqrtf(var + EPSV);
    coef[c] = a;
    coef[C + c] = be[c] - mean * a;
  }
}

// ---------------------------------------------------------------------------
// h1 helpers (v8). h1f row r <-> t = t0 - HOF + r.
// ---------------------------------------------------------------------------
template<int CPT, int RMAX, int HOF>
__device__ __forceinline__ void h1_compute(
    int t0, const float* xs, const float* w1T,
    const float* __restrict__ coef1, const float* __restrict__ b1c,
    unsigned short* h1f)
{
  const int cgr = threadIdx.x & 15, cg2 = threadIdx.x >> 4;
  const int r0 = cg2 * CPT;
  float xv[2][16];
  #pragma unroll
  for (int i2 = 0; i2 < 2; ++i2) {
    const float* xp = &xs[i2 * 168 + r0];
    float4 p0 = *reinterpret_cast<const float4*>(xp);
    float4 p1 = *reinterpret_cast<const float4*>(xp + 4);
    float4 p2 = *reinterpret_cast<const float4*>(xp + 8);
    float4 p3 = *reinterpret_cast<const float4*>(xp + 12);
    xv[i2][0] = p0.x;  xv[i2][1] = p0.y;  xv[i2][2] = p0.z;  xv[i2][3] = p0.w;
    xv[i2][4] = p1.x;  xv[i2][5] = p1.y;  xv[i2][6] = p1.z;  xv[i2][7] = p1.w;
    xv[i2][8] = p2.x;  xv[i2][9] = p2.y;  xv[i2][10] = p2.z; xv[i2][11] = p2.w;
    xv[i2][12] = p3.x; xv[i2][13] = p3.y; xv[i2][14] = p3.z; xv[i2][15] = p3.w;
  }
  #pragma unroll
  for (int half = 0; half < 2; ++half) {
    const int chA = cgr * 4 + half * 2;
    float w0[14], w1[14];
    #pragma unroll
    for (int q = 0; q < 14; ++q) {
      w0[q] = w1T[q * 64 + chA];
      w1[q] = w1T[q * 64 + chA + 1];
    }
    const float a1A = coef1[chA],     d1A = coef1[64 + chA],     bA = b1c[chA];
    const float a1B = coef1[chA + 1], d1B = coef1[64 + chA + 1], bB = b1c[chA + 1];
    #pragma unroll
    for (int cc = 0; cc < CPT; ++cc) {
      int r = r0 + cc;
      if (r < RMAX) {
        int t = t0 - HOF + r;
        bool ok = (t >= 0) && (t < TLEN);
        float aA = bA, aB = bB;
        #pragma unroll
        for (int i2 = 0; i2 < 2; ++i2)
          #pragma unroll
          for (int k = 0; k < 7; ++k) {
            aA += xv[i2][cc + k] * w0[i2 * 7 + k];
            aB += xv[i2][cc + k] * w1[i2 * 7 + k];
          }
        float vA = lrelu(a1A * aA + d1A);
        float vB = lrelu(a1B * aB + d1B);
        unsigned uu = (unsigned)h16(ok ? vA : 0.f) |
                      ((unsigned)h16(ok ? vB : 0.f) << 16);
        *(unsigned*)(h1f + r * 72 + chA) = uu;
      }
    }
  }
}

__device__ __forceinline__ void stage_x_w1(
    int t0, int xoff, const float* __restrict__ xin, int b,
    const float* __restrict__ W1c, float* xs, float* w1T)
{
  for (int e = threadIdx.x; e < 2 * 168; e += 256) {
    int i = e / 168, j = e % 168;
    int tg = t0 - xoff + j;
    xs[e] = (tg >= 0 && tg < TLEN) ? xin[(b * NICH + i) * TLEN + tg] : 0.f;
  }
  for (int e = threadIdx.x; e < 14 * 64; e += 256) {
    int q = e >> 6, ch = e & 63;
    w1T[e] = W1c[ch * 14 + q];
  }
}

// ---------------------------------------------------------------------------
// Kernel 3/9: conv2 via fp16 MFMA, stats only (v8, unchanged).
// ---------------------------------------------------------------------------
__global__ __launch_bounds__(256, 4) void conv2_stats_mfma(
    const float* __restrict__ xin,
    const float* __restrict__ W1c, const float* __restrict__ b1c,
    const float* __restrict__ coef1,
    const unsigned short* __restrict__ w2f,
    const float* __restrict__ b2c,
    float* __restrict__ partials)
{
  const int b  = blockIdx.x >> 10;
  const int t0 = (blockIdx.x & 1023) * 128;

  __shared__ __align__(16) char smem[24224];
  unsigned short* h1f = (unsigned short*)smem;   // [134][72], r <-> t0-3+r
  float* xs   = (float*)(smem + 19296);          // [2][168], j <-> t0-6+j
  float* w1T  = (float*)(smem + 20640);          // [14][64]
  float* redS = (float*)smem;                    // [128][17] (aliases h1f, late)
  float* redSS= (float*)(smem + 8704);

  stage_x_w1(t0, 6, xin, b, W1c, xs, w1T);
  __syncthreads();
  h1_compute<9, 134, 3>(t0, xs, w1T, coef1, b1c, h1f);
  __syncthreads();

  const int lane = threadIdx.x & 63;
  const int wv = threadIdx.x >> 6;
  const int mn = lane & 15, quad = lane >> 4;

  f32x4 acc[2][8];
  #pragma unroll
  for (int mt = 0; mt < 2; ++mt)
    #pragma unroll
    for (int nt = 0; nt < 8; ++nt) {
      f32x4 z = {0.f, 0.f, 0.f, 0.f};
      acc[mt][nt] = z;
    }

  f16x8 ca[2], na[2];
  auto loadA = [&](int c, f16x8 (&A)[2]) {
    #pragma unroll
    for (int mt = 0; mt < 2; ++mt)
      A[mt] = *(const f16x8*)(w2f + (c * 8 + wv * 2 + mt) * 512 + mn * 32 + quad * 8);
  };
  loadA(0, ca);
  #pragma unroll
  for (int c = 0; c < 14; ++c) {
    if (c < 13) loadA(c + 1, na);
    const int tap = c >> 1;
    const int ch0 = (c & 1) * 32 + quad * 8;
    #pragma unroll
    for (int nt = 0; nt < 8; ++nt) {
      f16x8 bb = *(const f16x8*)(h1f + (nt * 16 + mn + tap) * 72 + ch0);
      acc[0][nt] = __builtin_amdgcn_mfma_f32_16x16x32_f16(ca[0], bb, acc[0][nt], 0, 0, 0);
      acc[1][nt] = __builtin_amdgcn_mfma_f32_16x16x32_f16(ca[1], bb, acc[1][nt], 0, 0, 0);
    }
    ca[0] = na[0]; ca[1] = na[1];
  }
  __syncthreads();

  #pragma unroll
  for (int mt = 0; mt < 2; ++mt)
    #pragma unroll
    for (int r = 0; r < 4; ++r) {
      int o = (wv * 2 + mt) * 16 + quad * 4 + r;
      float bo = b2c[o];
      float s = 0.f, ss = 0.f;
      #pragma unroll
      for (int nt = 0; nt < 8; ++nt) {
        float v = acc[mt][nt][r] + bo;
        s += v; ss += v * v;
      }
      redS[o * 17 + mn] = s;
      redSS[o * 17 + mn] = ss;
    }
  __syncthreads();
  {
    int o = threadIdx.x & 127;
    const float* src = (threadIdx.x < 128) ? redS : redSS;
    float s = 0.f;
    #pragma unroll
    for (int j = 0; j < 16; ++j) s += src[o * 17 + j];
    partials[blockIdx.x * 256 + threadIdx.x] = s;
  }
}

// ---------------------------------------------------------------------------
// Kernel 5: fp32 recompute of c2 head + bn2 + conv3(t=0) + tanh -> HRTF gather.
// ---------------------------------------------------------------------------
__global__ __launch_bounds__(256) void finalize_spatial(
    const float* __restrict__ x,
    const float* __restrict__ W1c, const float* __restrict__ b1c,
    const float* __restrict__ coef1,
    const float* __restrict__ W2c, const float* __restrict__ b2c,
    const float* __restrict__ coef2,
    const float* __restrict__ W3c, const float* __restrict__ b3c,
    const float* __restrict__ hrtf, float* __restrict__ wgbuf)
{
  __shared__ float xl[NB * 2 * 16];
  __shared__ float h1l[NB * 64 * 10];
  __shared__ float h2l[NB * NH2 * 4];
  __shared__ float sp[48];
  const int tid = threadIdx.x;
  {
    int bb = tid >> 5, i = (tid >> 4) & 1, j = tid & 15;
    int t = j - 6;
    xl[tid] = (t >= 0) ? x[(bb * 2 + i) * TLEN + t] : 0.f;
  }
  __syncthreads();
  for (int e = tid; e < NB * 64; e += 256) {
    int bb = e >> 6, ch = e & 63;
    float a1 = coef1[ch], d1 = coef1[64 + ch], bo = b1c[ch];
    for (int tt = 0; tt < 10; ++tt) {
      float acc = bo;
      #pragma unroll
      for (int i2 = 0; i2 < 2; ++i2)
        #pragma unroll
        for (int k = 0; k < 7; ++k)
          acc += xl[(bb * 2 + i2) * 16 + tt + k] * W1c[ch * 14 + i2 * 7 + k];
      float v = lrelu(a1 * acc + d1);
      h1l[(bb * 64 + ch) * 10 + tt] = (tt >= 3) ? v : 0.f;
    }
  }
  __syncthreads();
  for (int e = tid; e < NB * NH2; e += 256) {
    int bb = e >> 7, o = e & 127;
    float a2 = coef2[o], d2 = coef2[NH2 + o], bo = b2c[o];
    float acc[4] = {bo, bo, bo, bo};
    for (int i = 0; i < 64; ++i)
      #pragma unroll
      for (int k = 0; k < 7; ++k) {
        float w = W2c[(o * 64 + i) * 7 + k];
        #pragma unroll
        for (int t = 0; t < 4; ++t)
          acc[t] += h1l[(bb * 64 + i) * 10 + t + k] * w;
      }
    #pragma unroll
    for (int t = 0; t < 4; ++t)
      h2l[(bb * NH2 + o) * 4 + t] = lrelu(a2 * acc[t] + d2);
  }
  __syncthreads();
  if (tid < 48) {
    int bb = tid / 6, c3 = tid % 6;
    float acc = b3c[c3];
    for (int c = 0; c < NH2; ++c)
      #pragma unroll
      for (int k = 3; k < 7; ++k)
        acc += h2l[(bb * NH2 + c) * 4 + (k - 3)] * W3c[(c3 * NH2 + c) * 7 + k];
    sp[tid] = tanhf(acc);
  }
  __syncthreads();
  if (tid < 16) {
    int bb = tid >> 1, i = tid & 1;
    float az = (sp[bb * 6 + i * 3 + 0] + 1.f) * 0.5f * 11.f;
    float el = (sp[bb * 6 + i * 3 + 1] + 1.f) * 0.5f * 4.f;
    float dist = (sp[bb * 6 + i * 3 + 2] + 1.f) * 0.5f * 0.9f + 0.1f;
    int azi = min(max((int)az, 0), 11);
    int eli = min(max((int)el, 0), 4);
    int idx = eli * 12 + azi;
    for (int e = 0; e < 14; ++e)
      wgbuf[(bb * 2 + i) * 14 + e] = hrtf[idx * 14 + e] * dist;
  }
}

// ---------------------------------------------------------------------------
// Kernel 6: summed[b,c,t] = sum_{i,k} x[b,i,t+k-3] * wg[b,i,c,k]
// ---------------------------------------------------------------------------
__global__ __launch_bounds__(256) void mix_kernel(
    const float* __restrict__ x, const float* __restrict__ wgbuf,
    float* __restrict__ summed)
{
  const int b = blockIdx.x >> 7;
  const int t0 = (blockIdx.x & 127) * 1024 + threadIdx.x * 4;
  float wv[2][2][7];
  #pragma unroll
  for (int i = 0; i < 2; ++i)
    #pragma unroll
    for (int c = 0; c < 2; ++c)
      #pragma unroll
      for (int k = 0; k < 7; ++k)
        wv[i][c][k] = wgbuf[(b * 2 + i) * 14 + c * 7 + k];
  float acc[2][4] = {{0.f, 0.f, 0.f, 0.f}, {0.f, 0.f, 0.f, 0.f}};
  #pragma unroll
  for (int i = 0; i < 2; ++i) {
    float xl[12];
    #pragma unroll
    for (int j = 0; j < 12; ++j) {
      int tg = t0 - 4 + j;
      xl[j] = (tg >= 0 && tg < TLEN) ? x[(b * 2 + i) * TLEN + tg] : 0.f;
    }
    #pragma unroll
    for (int c = 0; c < 2; ++c)
      #pragma unroll
      for (int k = 0; k < 7; ++k)
        #pragma unroll
        for (int tt = 0; tt < 4; ++tt)
          acc[c][tt] += xl[tt + k + 1] * wv[i][c][k];
  }
  #pragma unroll
  for (int c = 0; c < 2; ++c)
    *reinterpret_cast<float4*>(&summed[(b * 2 + c) * TLEN + t0]) =
        make_float4(acc[c][0], acc[c][1], acc[c][2], acc[c][3]);
}

// ---------------------------------------------------------------------------
// Kernel 11: 120-col tile, grid (1093, NB). conv2 now mirrors the stats
// kernel: wave owns M-tiles {2w,2w+1} x all 8 N-tiles, A register-prefetched.
// Then bn2+lrelu -> h2t fp16 [col][ch] -> conv3 MFMA -> dq -> gather + tanh.
// ---------------------------------------------------------------------------
__global__ __launch_bounds__(256, 4) void conv2_final_mfma(
    const float* __restrict__ xin,
    const float* __restrict__ W1c, const float* __restrict__ b1c,
    const float* __restrict__ coef1,
    const unsigned short* __restrict__ w2f,
    const float* __restrict__ b2c, const float* __restrict__ coef2,
    const unsigned short* __restrict__ w3g, const float* __restrict__ rb3c,
    float* __restrict__ out)
{
  const int b  = blockIdx.y;
  const int t0 = blockIdx.x * FT;

  __shared__ __align__(16) char smem[39936];
  float* xs  = (float*)smem;                             // [2][168], j <-> t0-9+j
  float* w1T = (float*)(smem + 1344);                    // [14][64]
  unsigned short* h1f = (unsigned short*)(smem + 4928);  // [134][72], r <-> t0-6+r
  unsigned short* h2t = (unsigned short*)smem;           // [128][136] (late alias)
  unsigned short* dq  = (unsigned short*)(smem + 34816); // [128][20]

  stage_x_w1(t0, 9, xin, b, W1c, xs, w1T);
  __syncthreads();
  h1_compute<9, 134, 6>(t0, xs, w1T, coef1, b1c, h1f);
  __syncthreads();

  const int lane = threadIdx.x & 63;
  const int wv = threadIdx.x >> 6;
  const int mn = lane & 15, quad = lane >> 4;

  // ---- conv2: 14 K-chunks x 8 N-tiles x 2 M-tiles per wave, prefetched A ----
  f32x4 acc[2][8];
  #pragma unroll
  for (int mt = 0; mt < 2; ++mt)
    #pragma unroll
    for (int nt = 0; nt < 8; ++nt) {
      f32x4 z = {0.f, 0.f, 0.f, 0.f};
      acc[mt][nt] = z;
    }

  f16x8 ca[2], na[2];
  auto loadA = [&](int c, f16x8 (&A)[2]) {
    #pragma unroll
    for (int mt = 0; mt < 2; ++mt)
      A[mt] = *(const f16x8*)(w2f + (c * 8 + wv * 2 + mt) * 512 + mn * 32 + quad * 8);
  };
  loadA(0, ca);
  #pragma unroll
  for (int c = 0; c < 14; ++c) {
    if (c < 13) loadA(c + 1, na);
    const int tap = c >> 1;
    const int ch0 = (c & 1) * 32 + quad * 8;
    #pragma unroll
    for (int nt = 0; nt < 8; ++nt) {
      f16x8 bb = *(const f16x8*)(h1f + (nt * 16 + mn + tap) * 72 + ch0);
      acc[0][nt] = __builtin_amdgcn_mfma_f32_16x16x32_f16(ca[0], bb, acc[0][nt], 0, 0, 0);
      acc[1][nt] = __builtin_amdgcn_mfma_f32_16x16x32_f16(ca[1], bb, acc[1][nt], 0, 0, 0);
    }
    ca[0] = na[0]; ca[1] = na[1];
  }
  __syncthreads();   // h1f/xs/w1T dead; h2t aliases them

  // ---- bn2 + lrelu -> h2t fp16 [j'][ch]; j' <-> t = t0-3+j' ----
  #pragma unroll
  for (int nt = 0; nt < 8; ++nt) {
    int jp = nt * 16 + mn;
    int t = t0 - 3 + jp;
    bool ok = (t >= 0) && (t < TLEN);
    #pragma unroll
    for (int mt = 0; mt < 2; ++mt) {
      int obase = (wv * 2 + mt) * 16 + quad * 4;
      unsigned us[4];
      #pragma unroll
      for (int r = 0; r < 4; ++r) {
        int o = obase + r;
        float v = acc[mt][nt][r] + b2c[o];
        v = lrelu(coef2[o] * v + coef2[NH2 + o]);
        us[r] = h16(ok ? v : 0.f);
      }
      *(uint2*)(h2t + jp * 136 + obase) =
          make_uint2(us[0] | (us[1] << 16), us[2] | (us[3] << 16));
    }
  }
  __syncthreads();

  // ---- conv3: D'[m=oc*7+tap][n=j'] = sum_ch W3 * h2 ----
  const int nt0 = wv * 2;
  f32x4 acc3[2];
  #pragma unroll
  for (int i = 0; i < 2; ++i) {
    f32x4 z = {0.f, 0.f, 0.f, 0.f};
    acc3[i] = z;
  }
  #pragma unroll
  for (int c = 0; c < 4; ++c) {
    f16x8 A3 = *(const f16x8*)(w3g + c * 512 + mn * 32 + quad * 8);
    #pragma unroll
    for (int i = 0; i < 2; ++i) {
      f16x8 bb = *(const f16x8*)(h2t + ((nt0 + i) * 16 + mn) * 136 + c * 32 + quad * 8);
      acc3[i] = __builtin_amdgcn_mfma_f32_16x16x32_f16(A3, bb, acc3[i], 0, 0, 0);
    }
  }
  #pragma unroll
  for (int i = 0; i < 2; ++i) {
    int n = (nt0 + i) * 16 + mn;
    unsigned us[4];
    #pragma unroll
    for (int r = 0; r < 4; ++r) us[r] = h16(acc3[i][r]);
    *(uint2*)(dq + n * 20 + quad * 4) =
        make_uint2(us[0] | (us[1] << 16), us[2] | (us[3] << 16));
  }
  __syncthreads();

  // ---- gather: out[oc][u] = tanh(b3 + sum_tap D'[u+tap][oc*7+tap]) ----
  {
    int tid = threadIdx.x;
    if (tid < 240) {
      int oc = (tid >= FT) ? 1 : 0;
      int u = tid - oc * FT;
      float s = rb3c[oc];
      #pragma unroll
      for (int tap = 0; tap < 7; ++tap)
        s += fh16(dq[(u + tap) * 20 + oc * 7 + tap]);
      int t = t0 + u;
      if (t < TLEN) out[(b * 2 + oc) * TLEN + t] = tanhf(s);
    }
  }
}

// ---------------------------------------------------------------------------
extern "C" void kernel_launch(void* const* d_in, const int* in_sizes, int n_in,
                              void* d_out, int out_size, void* d_ws, size_t ws_size,
                              hipStream_t stream)
{
  (void)in_sizes; (void)n_in; (void)out_size; (void)ws_size;
  const float* x    = (const float*)d_in[0];
  const float* W1   = (const float*)d_in[1];
  const float* b1   = (const float*)d_in[2];
  const float* g1   = (const float*)d_in[3];
  const float* be1  = (const float*)d_in[4];
  const float* W2   = (const float*)d_in[5];
  const float* b2   = (const float*)d_in[6];
  const float* g2   = (const float*)d_in[7];
  const float* be2  = (const float*)d_in[8];
  const float* W3   = (const float*)d_in[9];
  const float* b3   = (const float*)d_in[10];
  const float* hrtf = (const float*)d_in[11];
  const float* RW1  = (const float*)d_in[12];
  const float* rb1  = (const float*)d_in[13];
  const float* rg1  = (const float*)d_in[14];
  const float* rbe1 = (const float*)d_in[15];
  const float* RW2  = (const float*)d_in[16];
  const float* rb2  = (const float*)d_in[17];
  const float* rg2  = (const float*)d_in[18];
  const float* rbe2 = (const float*)d_in[19];
  const float* RW3  = (const float*)d_in[20];
  const float* rb3  = (const float*)d_in[21];
  float* out = (float*)d_out;

  // d_out doubles as the 8192x256-f stats-partials buffer (lifetime ends
  // before conv2_final_mfma writes output).
  float* partialsB = (float*)d_out;

  char* ws = (char*)d_ws;
  float* partialsA      = (float*)(ws + 0);        // 524,288 B (xcorr partials)
  float* summed         = (float*)(ws + 524288);   // 8,388,608 B
  float* coef1          = (float*)(ws + 8912896);  // 128 f
  float* coef2          = (float*)(ws + 8913408);  // 256 f
  float* coefR1         = (float*)(ws + 8914432);  // 128 f
  float* coefR2         = (float*)(ws + 8914944);  // 256 f
  float* wgbuf          = (float*)(ws + 8915968);  // 224 f
  unsigned short* w2sp  = (unsigned short*)(ws + 8916992);  // 114,688 B
  unsigned short* w2re  = (unsigned short*)(ws + 9031680);  // 114,688 B
  unsigned short* w3g   = (unsigned short*)(ws + 9146368);  // 4,096 B
  // total ws use: 9,150,464 bytes

  prep_weights<<<456, 256, 0, stream>>>(W2, RW2, RW3, w2sp, w2re, w3g);
  // ---- spatial parameter network ----
  xcorr_stats<<<512, 256, 0, stream>>>(x, partialsA);
  assemble_coef1<<<1, 256, 0, stream>>>(partialsA, 512, W1, b1, g1, be1, coef1);
  conv2_stats_mfma<<<8192, 256, 0, stream>>>(x, W1, b1, coef1, w2sp, b2, partialsB);
  reduce_coef<<<128, 256, 0, stream>>>(partialsB, 8192, 128, g2, be2, coef2);
  finalize_spatial<<<1, 256, 0, stream>>>(x, W1, b1, coef1, W2, b2, coef2,
                                          W3, b3, hrtf, wgbuf);
  // ---- HRTF mixing ----
  mix_kernel<<<1024, 256, 0, stream>>>(x, wgbuf, summed);
  // ---- binaural renderer ----
  xcorr_stats<<<512, 256, 0, stream>>>(summed, partialsA);
  assemble_coef1<<<1, 256, 0, stream>>>(partialsA, 512, RW1, rb1, rg1, rbe1, coefR1);
  conv2_stats_mfma<<<8192, 256, 0, stream>>>(summed, RW1, rb1, coefR1,
                                             w2re, rb2, partialsB);
  reduce_coef<<<128, 256, 0, stream>>>(partialsB, 8192, 128, rg2, rbe2, coefR2);
  conv2_final_mfma<<<dim3(FGRID, NB), 256, 0, stream>>>(
      summed, RW1, rb1, coefR1, w2re, rb2, coefR2, w3g, rb3, out);
}

// Round 10
// 665.788 us; speedup vs baseline: 1.4980x; 1.4980x over previous
//
#include <hip/hip_runtime.h>
#include <hip/hip_fp16.h>
#include <cstddef>

// ---------------------------------------------------------------------------
// SpatialAudioRenderer on MI355X — v10: conv1 on MFMA + parallel assemble.
//
// R9: final 240us (VALU 55% — scalar h1 phase dominates), total regressed to
// 997 (serial 1-wave assemble_coef1 ~2x bubbles). v10:
//  - conv1 as 16x16x32 MFMA (K=i*16+kk padded; im2col B-tile in LDS; b1
//    folded into BN affine) in stats & final kernels -> kills the h1 VALU wall
//  - assemble_coef1 reduction parallelized (240 thr + LDS tree)
// ---------------------------------------------------------------------------

#define TLEN 131072
#define NB 8
#define NICH 2
#define NHID 64
#define NH2 128
#define EPSV 1e-5f
#define CNTF 1048576.0f  // NB * TLEN
#define FT 120           // final-kernel output tile
#define FGRID 1093       // ceil(TLEN / FT)
#define XCH 2048         // xcorr t-chunk

typedef _Float16 f16x8 __attribute__((ext_vector_type(8)));
typedef float f32x4 __attribute__((ext_vector_type(4)));

__device__ __forceinline__ float lrelu(float v) { return v >= 0.f ? v : 0.2f * v; }
__device__ __forceinline__ unsigned short h16(float v) {
  return __half_as_ushort(__float2half(v));
}
__device__ __forceinline__ float fh16(unsigned short u) {
  return __half2float(__ushort_as_half(u));
}

// ---------------------------------------------------------------------------
// Kernel 0: weight prep.
//  w2sp/w2re: fragment-contiguous conv2 A (v8 layout).
//  w3g:       conv3 A' [c*512 + m*32 + ch%32].
//  w1sp/w1re: conv1 A, frag m: [m*512 + mn*32 + (i*16+kk)], kk<7 valid.
// ---------------------------------------------------------------------------
__global__ __launch_bounds__(256) void prep_weights(
    const float* __restrict__ W2c, const float* __restrict__ RW2c,
    const float* __restrict__ RW3c,
    const float* __restrict__ W1c, const float* __restrict__ RW1c,
    unsigned short* __restrict__ w2sp, unsigned short* __restrict__ w2re,
    unsigned short* __restrict__ w3g,
    unsigned short* __restrict__ w1sp, unsigned short* __restrict__ w1re)
{
  int e = blockIdx.x * 256 + threadIdx.x;
  if (e < 114688) {
    int e2 = (e >= 57344) ? e - 57344 : e;
    int frag = e2 >> 9, within = e2 & 511;
    int c = frag >> 3, mt = frag & 7;
    int mn = within >> 5, kk = within & 31;
    int o = mt * 16 + mn;
    int tap = c >> 1, ch = (c & 1) * 32 + kk;
    const float* src = (e >= 57344) ? RW2c : W2c;
    unsigned short* dst = (e >= 57344) ? w2re : w2sp;
    dst[e2] = h16(src[(o * 64 + ch) * 7 + tap]);
  } else if (e < 116736) {
    int e2 = e - 114688;
    int c = e2 >> 9, within = e2 & 511;
    int m = within >> 5, kk = within & 31;
    int ch = c * 32 + kk;
    w3g[e2] = (m < 14) ? h16(RW3c[((m / 7) * 128 + ch) * 7 + (m % 7)])
                       : (unsigned short)0;
  } else if (e < 120832) {
    int e2 = e - 116736;
    int which = (e2 >= 2048);
    int e3 = e2 & 2047;
    int m = e3 >> 9, w = e3 & 511;
    int mn = w >> 5, K = w & 31;
    int i = K >> 4, kk = K & 15;
    const float* src = which ? RW1c : W1c;
    unsigned short* dst = which ? w1re : w1sp;
    dst[e3] = (kk < 7) ? h16(src[(m * 16 + mn) * 14 + i * 7 + kk])
                       : (unsigned short)0;
  }
}

// ---------------------------------------------------------------------------
// Kernel A: input autocorrelation partials (30 floats/block).
// ---------------------------------------------------------------------------
__global__ __launch_bounds__(256) void xcorr_stats(
    const float* __restrict__ z, float* __restrict__ partials)
{
  const int b = blockIdx.x >> 6;
  const int t0 = (blockIdx.x & 63) * XCH;
  __shared__ float zs[2][XCH + 8];
  __shared__ float redx[4][30];
  for (int i = 0; i < 2; ++i)
    for (int j = threadIdx.x; j < XCH + 7; j += 256) {
      int tg = t0 + j;
      zs[i][j] = (tg < TLEN) ? z[(b * 2 + i) * TLEN + tg] : 0.f;
    }
  __syncthreads();

  float acc[30];
  #pragma unroll
  for (int q = 0; q < 30; ++q) acc[q] = 0.f;
  const int tb = threadIdx.x * 8;
  #pragma unroll
  for (int tt = 0; tt < 8; ++tt) {
    int j = tb + tt;
    float z0 = zs[0][j], z1 = zs[1][j];
    acc[28] += z0; acc[29] += z1;
    #pragma unroll
    for (int d = 0; d < 7; ++d) {
      float a0 = zs[0][j + d], a1 = zs[1][j + d];
      acc[d]      += z0 * a0;
      acc[7 + d]  += z0 * a1;
      acc[14 + d] += z1 * a0;
      acc[21 + d] += z1 * a1;
    }
  }
  #pragma unroll
  for (int q = 0; q < 30; ++q)
    #pragma unroll
    for (int m = 1; m <= 32; m <<= 1)
      acc[q] += __shfl_xor(acc[q], m, 64);
  const int lane = threadIdx.x & 63, wv = threadIdx.x >> 6;
  if (lane == 0)
    #pragma unroll
    for (int q = 0; q < 30; ++q) redx[wv][q] = acc[q];
  __syncthreads();
  if (threadIdx.x < 30)
    partials[blockIdx.x * 30 + threadIdx.x] =
        redx[0][threadIdx.x] + redx[1][threadIdx.x] +
        redx[2][threadIdx.x] + redx[3][threadIdx.x];
}

// ---------------------------------------------------------------------------
// Kernel B: assemble coef1 from Rx/A1 (parallel reduction: 8 chunks x 30 q).
// ---------------------------------------------------------------------------
__global__ __launch_bounds__(256) void assemble_coef1(
    const float* __restrict__ partials, int nblocks,
    const float* __restrict__ W1c, const float* __restrict__ b1c,
    const float* __restrict__ g, const float* __restrict__ be,
    float* __restrict__ coef)
{
  __shared__ float R[30];
  __shared__ float pr[8][30];
  __shared__ float w1s[64 * 14];
  for (int e = threadIdx.x; e < 64 * 14; e += 256) w1s[e] = W1c[e];
  if (threadIdx.x < 240) {
    int q = threadIdx.x % 30, chunk = threadIdx.x / 30;
    float s = 0.f;
    for (int j = chunk; j < nblocks; j += 8) s += partials[j * 30 + q];
    pr[chunk][q] = s;
  }
  __syncthreads();
  if (threadIdx.x < 30) {
    float s = 0.f;
    #pragma unroll
    for (int c = 0; c < 8; ++c) s += pr[c][threadIdx.x];
    R[threadIdx.x] = s;
  }
  __syncthreads();
  if (threadIdx.x < 64) {
    int o = threadIdx.x;
    const float* w = &w1s[o * 14];
    float b1v = b1c[o];
    float sy = 0.f;
    #pragma unroll
    for (int i = 0; i < 2; ++i)
      #pragma unroll
      for (int k = 0; k < 7; ++k) sy += w[i * 7 + k] * R[28 + i];
    float syy = 0.f;
    #pragma unroll
    for (int i = 0; i < 2; ++i)
      #pragma unroll
      for (int k = 0; k < 7; ++k) {
        float wv = w[i * 7 + k];
        #pragma unroll
        for (int i2 = 0; i2 < 2; ++i2)
          #pragma unroll
          for (int k2 = 0; k2 < 7; ++k2) {
            int d = k2 - k;
            float r = (d >= 0) ? R[i * 14 + i2 * 7 + d]
                               : R[i2 * 14 + i * 7 - d];
            syy += wv * w[i2 * 7 + k2] * r;
          }
      }
    float S1 = CNTF * b1v + sy;
    float S2 = 2.f * b1v * S1 - CNTF * b1v * b1v + syy;
    float mean = S1 / CNTF;
    float var = S2 / CNTF - mean * mean;
    float a = g[o] * rsqrtf(var + EPSV);
    coef[o] = a;
    coef[64 + o] = be[o] - mean * a;
  }
}

// ---------------------------------------------------------------------------
// Kernel 2: reduce conv2-stats partials -> bn affine coefs.
// ---------------------------------------------------------------------------
__global__ __launch_bounds__(256) void reduce_coef(
    const float* __restrict__ partials, int nblocks, int C,
    const float* __restrict__ g, const float* __restrict__ be,
    float* __restrict__ coef)
{
  const int c = blockIdx.x;
  float s = 0.f, ss = 0.f;
  for (int j = threadIdx.x; j < nblocks; j += 256) {
    s  += partials[j * 2 * C + c];
    ss += partials[j * 2 * C + C + c];
  }
  #pragma unroll
  for (int off = 32; off >= 1; off >>= 1) {
    s  += __shfl_down(s, off, 64);
    ss += __shfl_down(ss, off, 64);
  }
  __shared__ float rs[4], rss[4];
  const int lane = threadIdx.x & 63, wv = threadIdx.x >> 6;
  if (lane == 0) { rs[wv] = s; rss[wv] = ss; }
  __syncthreads();
  if (threadIdx.x == 0) {
    float st  = rs[0] + rs[1] + rs[2] + rs[3];
    float sst = rss[0] + rss[1] + rss[2] + rss[3];
    float mean = st / CNTF;
    float var  = sst / CNTF - mean * mean;
    float a = g[c] * rsqrtf(var + EPSV);
    coef[c] = a;
    coef[C + c] = be[c] - mean * a;
  }
}

// ---------------------------------------------------------------------------
// Shared: stage x (fp32, 168 cols) then h1 via MFMA.
// xs col j <-> t = t0 - HOF - 3 + j.  h1f row r <-> t = t0 - HOF + r.
// B tile xw[n][K=i*16+kk] = xs[i][n+kk] (kk<7), built in LDS; A from w1f.
// ---------------------------------------------------------------------------
__device__ __forceinline__ void stage_x(
    int t0, int xoff, const float* __restrict__ xin, int b, float* xs)
{
  for (int e = threadIdx.x; e < 2 * 168; e += 256) {
    int i = e / 168, j = e % 168;
    int tg = t0 - xoff + j;
    xs[e] = (tg >= 0 && tg < TLEN) ? xin[(b * NICH + i) * TLEN + tg] : 0.f;
  }
}

template<int HOF>
__device__ __forceinline__ void h1_mfma(
    int t0, const float* xs, unsigned short* xw,
    const unsigned short* __restrict__ w1f,
    const float* __restrict__ coef1, const float* __restrict__ b1c,
    unsigned short* h1f)
{
  // build im2col B tile: 144 rows x 32 halfs
  for (int e = threadIdx.x; e < 144 * 2; e += 256) {
    int n = e >> 1, i = e & 1;
    const float* xp = &xs[i * 168 + n];
    unsigned short hv[7];
    #pragma unroll
    for (int kk = 0; kk < 7; ++kk) hv[kk] = h16(xp[kk]);
    *(uint4*)(xw + n * 32 + i * 16) = make_uint4(
        hv[0] | ((unsigned)hv[1] << 16), hv[2] | ((unsigned)hv[3] << 16),
        hv[4] | ((unsigned)hv[5] << 16), (unsigned)hv[6]);
    *(uint4*)(xw + n * 32 + i * 16 + 8) = make_uint4(0, 0, 0, 0);
  }
  __syncthreads();

  const int lane = threadIdx.x & 63;
  const int wv = threadIdx.x >> 6;
  const int mn = lane & 15, quad = lane >> 4;
  f16x8 A1 = *(const f16x8*)(w1f + wv * 512 + mn * 32 + quad * 8);
  f32x4 acc1[9];
  #pragma unroll
  for (int nt = 0; nt < 9; ++nt) {
    f32x4 z = {0.f, 0.f, 0.f, 0.f};
    acc1[nt] = z;
  }
  #pragma unroll
  for (int nt = 0; nt < 9; ++nt) {
    f16x8 bb = *(const f16x8*)(xw + (nt * 16 + mn) * 32 + quad * 8);
    acc1[nt] = __builtin_amdgcn_mfma_f32_16x16x32_f16(A1, bb, acc1[nt], 0, 0, 0);
  }
  // epilogue: bn1 (b1 folded) + lrelu + OOB zero -> h1f[n][ch]
  const int ch0 = wv * 16 + quad * 4;
  float a1v[4], dd[4];
  #pragma unroll
  for (int r = 0; r < 4; ++r) {
    a1v[r] = coef1[ch0 + r];
    dd[r]  = coef1[64 + ch0 + r] + a1v[r] * b1c[ch0 + r];
  }
  #pragma unroll
  for (int nt = 0; nt < 9; ++nt) {
    int n = nt * 16 + mn;
    int t = t0 - HOF + n;
    bool ok = (t >= 0) && (t < TLEN);
    unsigned us[4];
    #pragma unroll
    for (int r = 0; r < 4; ++r) {
      float v = lrelu(a1v[r] * acc1[nt][r] + dd[r]);
      us[r] = h16(ok ? v : 0.f);
    }
    *(uint2*)(h1f + n * 72 + ch0) =
        make_uint2(us[0] | (us[1] << 16), us[2] | (us[3] << 16));
  }
}

// ---------------------------------------------------------------------------
// Kernel 3/9: conv2 via fp16 MFMA, stats only. 128 o x 128 t per block.
// h1 via MFMA; conv2 mapping unchanged (2M x 8N per wave, prefetched A).
// LDS 31,296 B.
// ---------------------------------------------------------------------------
__global__ __launch_bounds__(256, 4) void conv2_stats_mfma(
    const float* __restrict__ xin,
    const unsigned short* __restrict__ w1f, const float* __restrict__ b1c,
    const float* __restrict__ coef1,
    const unsigned short* __restrict__ w2f,
    const float* __restrict__ b2c,
    float* __restrict__ partials)
{
  const int b  = blockIdx.x >> 10;
  const int t0 = (blockIdx.x & 1023) * 128;

  __shared__ __align__(16) char smem[31296];
  unsigned short* h1f = (unsigned short*)smem;          // [144][72], r <-> t0-3+r
  float* xs = (float*)(smem + 20736);                   // [2][168], j <-> t0-6+j
  unsigned short* xw = (unsigned short*)(smem + 22080); // [144][32]
  float* redS = (float*)smem;                           // [128][17] (late alias)
  float* redSS= (float*)(smem + 8704);

  stage_x(t0, 6, xin, b, xs);
  __syncthreads();
  h1_mfma<3>(t0, xs, xw, w1f, coef1, b1c, h1f);
  __syncthreads();

  const int lane = threadIdx.x & 63;
  const int wv = threadIdx.x >> 6;
  const int mn = lane & 15, quad = lane >> 4;

  f32x4 acc[2][8];
  #pragma unroll
  for (int mt = 0; mt < 2; ++mt)
    #pragma unroll
    for (int nt = 0; nt < 8; ++nt) {
      f32x4 z = {0.f, 0.f, 0.f, 0.f};
      acc[mt][nt] = z;
    }

  f16x8 ca[2], na[2];
  auto loadA = [&](int c, f16x8 (&A)[2]) {
    #pragma unroll
    for (int mt = 0; mt < 2; ++mt)
      A[mt] = *(const f16x8*)(w2f + (c * 8 + wv * 2 + mt) * 512 + mn * 32 + quad * 8);
  };
  loadA(0, ca);
  #pragma unroll
  for (int c = 0; c < 14; ++c) {
    if (c < 13) loadA(c + 1, na);
    const int tap = c >> 1;
    const int ch0 = (c & 1) * 32 + quad * 8;
    #pragma unroll
    for (int nt = 0; nt < 8; ++nt) {
      f16x8 bb = *(const f16x8*)(h1f + (nt * 16 + mn + tap) * 72 + ch0);
      acc[0][nt] = __builtin_amdgcn_mfma_f32_16x16x32_f16(ca[0], bb, acc[0][nt], 0, 0, 0);
      acc[1][nt] = __builtin_amdgcn_mfma_f32_16x16x32_f16(ca[1], bb, acc[1][nt], 0, 0, 0);
    }
    ca[0] = na[0]; ca[1] = na[1];
  }
  __syncthreads();

  #pragma unroll
  for (int mt = 0; mt < 2; ++mt)
    #pragma unroll
    for (int r = 0; r < 4; ++r) {
      int o = (wv * 2 + mt) * 16 + quad * 4 + r;
      float bo = b2c[o];
      float s = 0.f, ss = 0.f;
      #pragma unroll
      for (int nt = 0; nt < 8; ++nt) {
        float v = acc[mt][nt][r] + bo;
        s += v; ss += v * v;
      }
      redS[o * 17 + mn] = s;
      redSS[o * 17 + mn] = ss;
    }
  __syncthreads();
  {
    int o = threadIdx.x & 127;
    const float* src = (threadIdx.x < 128) ? redS : redSS;
    float s = 0.f;
    #pragma unroll
    for (int j = 0; j < 16; ++j) s += src[o * 17 + j];
    partials[blockIdx.x * 256 + threadIdx.x] = s;
  }
}

// ---------------------------------------------------------------------------
// Kernel 5: fp32 recompute of c2 head + bn2 + conv3(t=0) + tanh -> HRTF gather.
// ---------------------------------------------------------------------------
__global__ __launch_bounds__(256) void finalize_spatial(
    const float* __restrict__ x,
    const float* __restrict__ W1c, const float* __restrict__ b1c,
    const float* __restrict__ coef1,
    const float* __restrict__ W2c, const float* __restrict__ b2c,
    const float* __restrict__ coef2,
    const float* __restrict__ W3c, const float* __restrict__ b3c,
    const float* __restrict__ hrtf, float* __restrict__ wgbuf)
{
  __shared__ float xl[NB * 2 * 16];
  __shared__ float h1l[NB * 64 * 10];
  __shared__ float h2l[NB * NH2 * 4];
  __shared__ float sp[48];
  const int tid = threadIdx.x;
  {
    int bb = tid >> 5, i = (tid >> 4) & 1, j = tid & 15;
    int t = j - 6;
    xl[tid] = (t >= 0) ? x[(bb * 2 + i) * TLEN + t] : 0.f;
  }
  __syncthreads();
  for (int e = tid; e < NB * 64; e += 256) {
    int bb = e >> 6, ch = e & 63;
    float a1 = coef1[ch], d1 = coef1[64 + ch], bo = b1c[ch];
    for (int tt = 0; tt < 10; ++tt) {
      float acc = bo;
      #pragma unroll
      for (int i2 = 0; i2 < 2; ++i2)
        #pragma unroll
        for (int k = 0; k < 7; ++k)
          acc += xl[(bb * 2 + i2) * 16 + tt + k] * W1c[ch * 14 + i2 * 7 + k];
      float v = lrelu(a1 * acc + d1);
      h1l[(bb * 64 + ch) * 10 + tt] = (tt >= 3) ? v : 0.f;
    }
  }
  __syncthreads();
  for (int e = tid; e < NB * NH2; e += 256) {
    int bb = e >> 7, o = e & 127;
    float a2 = coef2[o], d2 = coef2[NH2 + o], bo = b2c[o];
    float acc[4] = {bo, bo, bo, bo};
    for (int i = 0; i < 64; ++i)
      #pragma unroll
      for (int k = 0; k < 7; ++k) {
        float w = W2c[(o * 64 + i) * 7 + k];
        #pragma unroll
        for (int t = 0; t < 4; ++t)
          acc[t] += h1l[(bb * 64 + i) * 10 + t + k] * w;
      }
    #pragma unroll
    for (int t = 0; t < 4; ++t)
      h2l[(bb * NH2 + o) * 4 + t] = lrelu(a2 * acc[t] + d2);
  }
  __syncthreads();
  if (tid < 48) {
    int bb = tid / 6, c3 = tid % 6;
    float acc = b3c[c3];
    for (int c = 0; c < NH2; ++c)
      #pragma unroll
      for (int k = 3; k < 7; ++k)
        acc += h2l[(bb * NH2 + c) * 4 + (k - 3)] * W3c[(c3 * NH2 + c) * 7 + k];
    sp[tid] = tanhf(acc);
  }
  __syncthreads();
  if (tid < 16) {
    int bb = tid >> 1, i = tid & 1;
    float az = (sp[bb * 6 + i * 3 + 0] + 1.f) * 0.5f * 11.f;
    float el = (sp[bb * 6 + i * 3 + 1] + 1.f) * 0.5f * 4.f;
    float dist = (sp[bb * 6 + i * 3 + 2] + 1.f) * 0.5f * 0.9f + 0.1f;
    int azi = min(max((int)az, 0), 11);
    int eli = min(max((int)el, 0), 4);
    int idx = eli * 12 + azi;
    for (int e = 0; e < 14; ++e)
      wgbuf[(bb * 2 + i) * 14 + e] = hrtf[idx * 14 + e] * dist;
  }
}

// ---------------------------------------------------------------------------
// Kernel 6: summed[b,c,t] = sum_{i,k} x[b,i,t+k-3] * wg[b,i,c,k]
// ---------------------------------------------------------------------------
__global__ __launch_bounds__(256) void mix_kernel(
    const float* __restrict__ x, const float* __restrict__ wgbuf,
    float* __restrict__ summed)
{
  const int b = blockIdx.x >> 7;
  const int t0 = (blockIdx.x & 127) * 1024 + threadIdx.x * 4;
  float wv[2][2][7];
  #pragma unroll
  for (int i = 0; i < 2; ++i)
    #pragma unroll
    for (int c = 0; c < 2; ++c)
      #pragma unroll
      for (int k = 0; k < 7; ++k)
        wv[i][c][k] = wgbuf[(b * 2 + i) * 14 + c * 7 + k];
  float acc[2][4] = {{0.f, 0.f, 0.f, 0.f}, {0.f, 0.f, 0.f, 0.f}};
  #pragma unroll
  for (int i = 0; i < 2; ++i) {
    float xl[12];
    #pragma unroll
    for (int j = 0; j < 12; ++j) {
      int tg = t0 - 4 + j;
      xl[j] = (tg >= 0 && tg < TLEN) ? x[(b * 2 + i) * TLEN + tg] : 0.f;
    }
    #pragma unroll
    for (int c = 0; c < 2; ++c)
      #pragma unroll
      for (int k = 0; k < 7; ++k)
        #pragma unroll
        for (int tt = 0; tt < 4; ++tt)
          acc[c][tt] += xl[tt + k + 1] * wv[i][c][k];
  }
  #pragma unroll
  for (int c = 0; c < 2; ++c)
    *reinterpret_cast<float4*>(&summed[(b * 2 + c) * TLEN + t0]) =
        make_float4(acc[c][0], acc[c][1], acc[c][2], acc[c][3]);
}

// ---------------------------------------------------------------------------
// Kernel 11: 120-col tile, grid (1093, NB). h1 via MFMA -> conv2 MFMA
// (prefetched A) -> bn2+lrelu -> h2t fp16 [col][ch] -> conv3 MFMA -> dq ->
// gather + tanh. LDS 39,936 B.
// ---------------------------------------------------------------------------
__global__ __launch_bounds__(256, 4) void conv2_final_mfma(
    const float* __restrict__ xin,
    const unsigned short* __restrict__ w1f, const float* __restrict__ b1c,
    const float* __restrict__ coef1,
    const unsigned short* __restrict__ w2f,
    const float* __restrict__ b2c, const float* __restrict__ coef2,
    const unsigned short* __restrict__ w3g, const float* __restrict__ rb3c,
    float* __restrict__ out)
{
  const int b  = blockIdx.y;
  const int t0 = blockIdx.x * FT;

  __shared__ __align__(16) char smem[39936];
  unsigned short* h1f = (unsigned short*)smem;          // [144][72], r <-> t0-6+r
  float* xs = (float*)(smem + 20736);                   // [2][168], j <-> t0-9+j
  unsigned short* xw = (unsigned short*)(smem + 22080); // [144][32]
  unsigned short* h2t = (unsigned short*)smem;          // [128][136] (late alias)
  unsigned short* dq  = (unsigned short*)(smem + 34816);// [128][20]

  stage_x(t0, 9, xin, b, xs);
  __syncthreads();
  h1_mfma<6>(t0, xs, xw, w1f, coef1, b1c, h1f);
  __syncthreads();

  const int lane = threadIdx.x & 63;
  const int wv = threadIdx.x >> 6;
  const int mn = lane & 15, quad = lane >> 4;

  // ---- conv2: 14 K-chunks x 8 N-tiles x 2 M-tiles per wave, prefetched A ----
  f32x4 acc[2][8];
  #pragma unroll
  for (int mt = 0; mt < 2; ++mt)
    #pragma unroll
    for (int nt = 0; nt < 8; ++nt) {
      f32x4 z = {0.f, 0.f, 0.f, 0.f};
      acc[mt][nt] = z;
    }

  f16x8 ca[2], na[2];
  auto loadA = [&](int c, f16x8 (&A)[2]) {
    #pragma unroll
    for (int mt = 0; mt < 2; ++mt)
      A[mt] = *(const f16x8*)(w2f + (c * 8 + wv * 2 + mt) * 512 + mn * 32 + quad * 8);
  };
  loadA(0, ca);
  #pragma unroll
  for (int c = 0; c < 14; ++c) {
    if (c < 13) loadA(c + 1, na);
    const int tap = c >> 1;
    const int ch0 = (c & 1) * 32 + quad * 8;
    #pragma unroll
    for (int nt = 0; nt < 8; ++nt) {
      f16x8 bb = *(const f16x8*)(h1f + (nt * 16 + mn + tap) * 72 + ch0);
      acc[0][nt] = __builtin_amdgcn_mfma_f32_16x16x32_f16(ca[0], bb, acc[0][nt], 0, 0, 0);
      acc[1][nt] = __builtin_amdgcn_mfma_f32_16x16x32_f16(ca[1], bb, acc[1][nt], 0, 0, 0);
    }
    ca[0] = na[0]; ca[1] = na[1];
  }
  __syncthreads();   // h1f/xs/xw dead; h2t aliases them

  // ---- bn2 + lrelu -> h2t fp16 [j'][ch]; j' <-> t = t0-3+j' ----
  #pragma unroll
  for (int nt = 0; nt < 8; ++nt) {
    int jp = nt * 16 + mn;
    int t = t0 - 3 + jp;
    bool ok = (t >= 0) && (t < TLEN);
    #pragma unroll
    for (int mt = 0; mt < 2; ++mt) {
      int obase = (wv * 2 + mt) * 16 + quad * 4;
      unsigned us[4];
      #pragma unroll
      for (int r = 0; r < 4; ++r) {
        int o = obase + r;
        float v = acc[mt][nt][r] + b2c[o];
        v = lrelu(coef2[o] * v + coef2[NH2 + o]);
        us[r] = h16(ok ? v : 0.f);
      }
      *(uint2*)(h2t + jp * 136 + obase) =
          make_uint2(us[0] | (us[1] << 16), us[2] | (us[3] << 16));
    }
  }
  __syncthreads();

  // ---- conv3: D'[m=oc*7+tap][n=j'] = sum_ch W3 * h2 ----
  const int nt0 = wv * 2;
  f32x4 acc3[2];
  #pragma unroll
  for (int i = 0; i < 2; ++i) {
    f32x4 z = {0.f, 0.f, 0.f, 0.f};
    acc3[i] = z;
  }
  #pragma unroll
  for (int c = 0; c < 4; ++c) {
    f16x8 A3 = *(const f16x8*)(w3g + c * 512 + mn * 32 + quad * 8);
    #pragma unroll
    for (int i = 0; i < 2; ++i) {
      f16x8 bb = *(const f16x8*)(h2t + ((nt0 + i) * 16 + mn) * 136 + c * 32 + quad * 8);
      acc3[i] = __builtin_amdgcn_mfma_f32_16x16x32_f16(A3, bb, acc3[i], 0, 0, 0);
    }
  }
  #pragma unroll
  for (int i = 0; i < 2; ++i) {
    int n = (nt0 + i) * 16 + mn;
    unsigned us[4];
    #pragma unroll
    for (int r = 0; r < 4; ++r) us[r] = h16(acc3[i][r]);
    *(uint2*)(dq + n * 20 + quad * 4) =
        make_uint2(us[0] | (us[1] << 16), us[2] | (us[3] << 16));
  }
  __syncthreads();

  // ---- gather: out[oc][u] = tanh(b3 + sum_tap D'[u+tap][oc*7+tap]) ----
  {
    int tid = threadIdx.x;
    if (tid < 240) {
      int oc = (tid >= FT) ? 1 : 0;
      int u = tid - oc * FT;
      float s = rb3c[oc];
      #pragma unroll
      for (int tap = 0; tap < 7; ++tap)
        s += fh16(dq[(u + tap) * 20 + oc * 7 + tap]);
      int t = t0 + u;
      if (t < TLEN) out[(b * 2 + oc) * TLEN + t] = tanhf(s);
    }
  }
}

// ---------------------------------------------------------------------------
extern "C" void kernel_launch(void* const* d_in, const int* in_sizes, int n_in,
                              void* d_out, int out_size, void* d_ws, size_t ws_size,
                              hipStream_t stream)
{
  (void)in_sizes; (void)n_in; (void)out_size; (void)ws_size;
  const float* x    = (const float*)d_in[0];
  const float* W1   = (const float*)d_in[1];
  const float* b1   = (const float*)d_in[2];
  const float* g1   = (const float*)d_in[3];
  const float* be1  = (const float*)d_in[4];
  const float* W2   = (const float*)d_in[5];
  const float* b2   = (const float*)d_in[6];
  const float* g2   = (const float*)d_in[7];
  const float* be2  = (const float*)d_in[8];
  const float* W3   = (const float*)d_in[9];
  const float* b3   = (const float*)d_in[10];
  const float* hrtf = (const float*)d_in[11];
  const float* RW1  = (const float*)d_in[12];
  const float* rb1  = (const float*)d_in[13];
  const float* rg1  = (const float*)d_in[14];
  const float* rbe1 = (const float*)d_in[15];
  const float* RW2  = (const float*)d_in[16];
  const float* rb2  = (const float*)d_in[17];
  const float* rg2  = (const float*)d_in[18];
  const float* rbe2 = (const float*)d_in[19];
  const float* RW3  = (const float*)d_in[20];
  const float* rb3  = (const float*)d_in[21];
  float* out = (float*)d_out;

  // d_out doubles as the 8192x256-f stats-partials buffer (lifetime ends
  // before conv2_final_mfma writes output).
  float* partialsB = (float*)d_out;

  char* ws = (char*)d_ws;
  float* partialsA      = (float*)(ws + 0);        // 524,288 B (xcorr partials)
  float* summed         = (float*)(ws + 524288);   // 8,388,608 B
  float* coef1          = (float*)(ws + 8912896);  // 128 f
  float* coef2          = (float*)(ws + 8913408);  // 256 f
  float* coefR1         = (float*)(ws + 8914432);  // 128 f
  float* coefR2         = (float*)(ws + 8914944);  // 256 f
  float* wgbuf          = (float*)(ws + 8915968);  // 224 f
  unsigned short* w2sp  = (unsigned short*)(ws + 8916992);  // 114,688 B
  unsigned short* w2re  = (unsigned short*)(ws + 9031680);  // 114,688 B
  unsigned short* w3g   = (unsigned short*)(ws + 9146368);  // 4,096 B
  unsigned short* w1sp  = (unsigned short*)(ws + 9150464);  // 4,096 B
  unsigned short* w1re  = (unsigned short*)(ws + 9154560);  // 4,096 B
  // total ws use: 9,158,656 bytes

  prep_weights<<<472, 256, 0, stream>>>(W2, RW2, RW3, W1, RW1,
                                        w2sp, w2re, w3g, w1sp, w1re);
  // ---- spatial parameter network ----
  xcorr_stats<<<512, 256, 0, stream>>>(x, partialsA);
  assemble_coef1<<<1, 256, 0, stream>>>(partialsA, 512, W1, b1, g1, be1, coef1);
  conv2_stats_mfma<<<8192, 256, 0, stream>>>(x, w1sp, b1, coef1, w2sp, b2,
                                             partialsB);
  reduce_coef<<<128, 256, 0, stream>>>(partialsB, 8192, 128, g2, be2, coef2);
  finalize_spatial<<<1, 256, 0, stream>>>(x, W1, b1, coef1, W2, b2, coef2,
                                          W3, b3, hrtf, wgbuf);
  // ---- HRTF mixing ----
  mix_kernel<<<1024, 256, 0, stream>>>(x, wgbuf, summed);
  // ---- binaural renderer ----
  xcorr_stats<<<512, 256, 0, stream>>>(summed, partialsA);
  assemble_coef1<<<1, 256, 0, stream>>>(partialsA, 512, RW1, rb1, rg1, rbe1, coefR1);
  conv2_stats_mfma<<<8192, 256, 0, stream>>>(summed, w1re, rb1, coefR1,
                                             w2re, rb2, partialsB);
  reduce_coef<<<128, 256, 0, stream>>>(partialsB, 8192, 128, rg2, rbe2, coefR2);
  conv2_final_mfma<<<dim3(FGRID, NB), 256, 0, stream>>>(
      summed, w1re, rb1, coefR1, w2re, rb2, coefR2, w3g, rb3, out);
}